// Round 3
// baseline (380.992 us; speedup 1.0000x reference)
//
#include <hip/hip_runtime.h>
#include <stdint.h>

#define P 2048
#define R 65536
#define DD 512
#define BM 128
#define BN 128
#define BK 32
#define NT (DD / BK)   // 16 K-tiles

typedef __attribute__((ext_vector_type(8))) short short8;
typedef __attribute__((ext_vector_type(4))) float f32x4;

__device__ inline unsigned short f2bf(float f) {
  unsigned int u = __float_as_uint(f);
  u += 0x7fffu + ((u >> 16) & 1u);   // round-to-nearest-even
  return (unsigned short)(u >> 16);
}

__device__ inline void gload_lds16(const void* g, void* l) {
  __builtin_amdgcn_global_load_lds(
      (const __attribute__((address_space(1))) unsigned int*)g,
      (__attribute__((address_space(3))) unsigned int*)l,
      16, 0, 0);
}

// ---- kernel 1: fp32 -> bf16 conversion + fp32 row norms; one wave per row ----
__global__ __launch_bounds__(256) void k_convert(
    const float* __restrict__ pred, const float* __restrict__ cand,
    unsigned short* __restrict__ Abf, unsigned short* __restrict__ Bbf,
    float* __restrict__ nx, float* __restrict__ ny,
    unsigned int* __restrict__ minp)
{
  if (blockIdx.x == 0 && threadIdx.x == 0) *minp = 0x7f800000u; // +inf bits
  int gw   = (blockIdx.x * 256 + threadIdx.x) >> 6;  // global wave = row
  int lane = threadIdx.x & 63;
  if (gw >= P + R) return;
  const float* src; unsigned short* dst; float* np;
  if (gw < P) { src = pred + (size_t)gw * DD; dst = Abf + (size_t)gw * DD; np = nx + gw; }
  else { int r = gw - P; src = cand + (size_t)r * DD; dst = Bbf + (size_t)r * DD; np = ny + r; }
  const float4* s4 = ((const float4*)src) + lane * 2;
  float4 v0 = s4[0], v1 = s4[1];
  float ss = v0.x*v0.x + v0.y*v0.y + v0.z*v0.z + v0.w*v0.w
           + v1.x*v1.x + v1.y*v1.y + v1.z*v1.z + v1.w*v1.w;
  union { unsigned short h[8]; uint4 v; } pk;
  pk.h[0]=f2bf(v0.x); pk.h[1]=f2bf(v0.y); pk.h[2]=f2bf(v0.z); pk.h[3]=f2bf(v0.w);
  pk.h[4]=f2bf(v1.x); pk.h[5]=f2bf(v1.y); pk.h[6]=f2bf(v1.z); pk.h[7]=f2bf(v1.w);
  *(uint4*)(dst + (size_t)lane * 8) = pk.v;
  #pragma unroll
  for (int off = 32; off; off >>= 1) ss += __shfl_down(ss, off, 64);
  if (lane == 0) *np = ss;
}

// ---- kernel 2: 128x128 bf16 MFMA tile GEMM (A·B^T), BK=32, 4 waves (2Mx2N),
//      per-wave 64x64 output, double-buffered LDS (32 KB total -> 4 blocks/CU,
//      16 waves/CU: cross-block TLP overlaps LDS-read phases with MFMA phases),
//      counted vmcnt(4) single-drain-free pipeline, setprio, XCD swizzle,
//      XOR-swizzled LDS (conflict-free), fused min epilogue.
//
// LDS layout per operand/buffer: row-major [128][32] bf16 (64 B/row, 4 chunks
// of 16 B). Stored chunk = data_chunk ^ ((row>>1)&3), applied via the GLOBAL
// source address (linear gload_lds dest + inverse-swizzled per-lane source).
// Frag read (lane = q*16+m reads row base+m, data chunk q) hits stored chunk
// q ^ ((m>>1)&3): per 128 B bank period the 8 (row&1, chunk) slots each get
// exactly 8 lanes -> same uniformity as the measured-conflict-free [r][64]
// layout of the previous rounds.
//
// Pipeline per iteration T (computing buf s=T&1):
//   stage(T+1 -> buf s^1)   [4 gload_lds; buf s^1 last read in iter T-1,
//                            ordered by iter T-1's end barrier]
//   s_waitcnt vmcnt(4)      [T's own 4 loads landed; T+1's stay in flight]
//   s_barrier               [all waves' T-loads landed]
//   8 x ds_read_b128 ; lgkmcnt(0) ; 16 x MFMA (independent accs)
//   s_barrier               [reads done before anyone re-stages this buf]
__global__ __launch_bounds__(256, 4) void k_gemm_min(
    const unsigned short* __restrict__ Abf, const unsigned short* __restrict__ Bbf,
    const float* __restrict__ nx, const float* __restrict__ ny,
    unsigned int* __restrict__ minp)
{
  __shared__ __align__(16) unsigned short As[2][BM * BK];   // 2 x 8 KB
  __shared__ __align__(16) unsigned short Bs[2][BN * BK];   // 2 x 8 KB
  __shared__ float wmin[4];

  const int tid  = threadIdx.x;
  const int wave = tid >> 6;          // 0..3
  const int lane = tid & 63;

  // XCD-aware bijective remap: 8192 blocks, 8 XCDs, 1024 contiguous per XCD.
  const int raw = blockIdx.x;
  const int wg  = (raw & 7) * 1024 + (raw >> 3);
  const int by  = wg & 15;            // A tile fast -> 16 adjacent wg share B tile
  const int bx  = wg >> 4;            // cand tile
  const int rowA0 = by * BM, rowB0 = bx * BN;
  const int wr = wave >> 1;           // 0..1 : M half
  const int wc = wave & 1;            // 0..1 : N half

  f32x4 zero = {0.f, 0.f, 0.f, 0.f};
  f32x4 acc[4][4];
  #pragma unroll
  for (int i = 0; i < 4; ++i)
    #pragma unroll
    for (int j = 0; j < 4; ++j) acc[i][j] = zero;

  // ---- staging: per tile, A (8 KB) = 8 wave-instrs of 16 rows; wave w covers
  // rows 32w..32w+31 via 2 instrs; same for B. lane L -> row-in-group L>>2,
  // stored chunk L&3, source data chunk (L&3)^((L>>3)&3)  [= cst ^ ((rloc>>1)&3)].
  const int rloc = lane >> 2;
  const int csrc = (lane & 3) ^ ((lane >> 3) & 3);
  const unsigned short* aS0 = Abf + (size_t)(rowA0 + wave * 32 + rloc) * DD + csrc * 8;
  const unsigned short* aS1 = aS0 + 16 * DD;
  const unsigned short* bS0 = Bbf + (size_t)(rowB0 + wave * 32 + rloc) * DD + csrc * 8;
  const unsigned short* bS1 = bS0 + 16 * DD;
  const int l0 = wave * 1024;         // shorts: group 2w
  const int l1 = wave * 1024 + 512;   // group 2w+1

#define STAGE(s, kk) do {                                   \
    gload_lds16(aS0 + (kk), &As[s][l0]);                    \
    gload_lds16(aS1 + (kk), &As[s][l1]);                    \
    gload_lds16(bS0 + (kk), &Bs[s][l0]);                    \
    gload_lds16(bS1 + (kk), &Bs[s][l1]);                    \
  } while (0)

  // fragment read geometry: row*BK shorts + swizzled chunk
  const int m = lane & 15, q = lane >> 4;
  const int swc  = (q ^ ((m >> 1) & 3)) * 8;            // shorts
  const int aOff = (wr * 64 + m) * BK + swc;
  const int bOff = (wc * 64 + m) * BK + swc;

  STAGE(0, 0);

  #pragma unroll 2
  for (int T = 0; T < NT; ++T) {
    const int s = T & 1;
    if (T + 1 < NT) {
      STAGE(s ^ 1, (T + 1) * BK);
      asm volatile("s_waitcnt vmcnt(4)" ::: "memory");   // tile T landed
    } else {
      asm volatile("s_waitcnt vmcnt(0)" ::: "memory");
    }
    __builtin_amdgcn_s_barrier();

    short8 af[4], bfr[4];
    #pragma unroll
    for (int i = 0; i < 4; ++i) af[i]  = *(const short8*)(&As[s][aOff + i * 16 * BK]);
    #pragma unroll
    for (int j = 0; j < 4; ++j) bfr[j] = *(const short8*)(&Bs[s][bOff + j * 16 * BK]);
    asm volatile("s_waitcnt lgkmcnt(0)" ::: "memory");
    __builtin_amdgcn_sched_barrier(0);
    __builtin_amdgcn_s_setprio(1);
    #pragma unroll
    for (int i = 0; i < 4; ++i)
      #pragma unroll
      for (int j = 0; j < 4; ++j)
        acc[i][j] = __builtin_amdgcn_mfma_f32_16x16x32_bf16(af[i], bfr[j], acc[i][j], 0, 0, 0);
    __builtin_amdgcn_s_setprio(0);
    __builtin_amdgcn_s_barrier();
  }
#undef STAGE

  // epilogue: d^2 = ||x||^2 + ||y||^2 - 2*dot ; C/D layout col=lane&15, row=q*4+reg
  float lmin = 3.4e38f;
  #pragma unroll
  for (int i = 0; i < 4; ++i) {
    const int mbase = rowA0 + wr * 64 + i * 16 + q * 4;
    float4 nxv = *(const float4*)(nx + mbase);
    #pragma unroll
    for (int j = 0; j < 4; ++j) {
      const int n = rowB0 + wc * 64 + j * 16 + m;
      const float nyv = ny[n];
      f32x4 a = acc[i][j];
      lmin = fminf(lmin, nxv.x + nyv - 2.0f * a[0]);
      lmin = fminf(lmin, nxv.y + nyv - 2.0f * a[1]);
      lmin = fminf(lmin, nxv.z + nyv - 2.0f * a[2]);
      lmin = fminf(lmin, nxv.w + nyv - 2.0f * a[3]);
    }
  }
  #pragma unroll
  for (int off = 32; off; off >>= 1) lmin = fminf(lmin, __shfl_down(lmin, off, 64));
  if (lane == 0) wmin[wave] = lmin;
  __syncthreads();
  if (tid == 0) {
    float mn = fminf(fminf(wmin[0], wmin[1]), fminf(wmin[2], wmin[3]));
    atomicMin(minp, __float_as_uint(fmaxf(mn, 0.0f)));
  }
}

// ---- fallback (only if ws too small): exact fp32 brute force ----
__global__ __launch_bounds__(64) void k_initmin(unsigned int* minp) {
  if (threadIdx.x == 0) *minp = 0x7f800000u;
}

__global__ __launch_bounds__(256) void k_brute(
    const float* __restrict__ pred, const float* __restrict__ cand,
    unsigned int* __restrict__ minp)
{
  __shared__ float yrow[DD];
  __shared__ float wm[4];
  const int c = blockIdx.x;
  for (int i = threadIdx.x; i < DD; i += 256) yrow[i] = cand[(size_t)c * DD + i];
  __syncthreads();
  float lmin = 3.4e38f;
  for (int p = threadIdx.x; p < P; p += 256) {
    const float* xp = pred + (size_t)p * DD;
    float s = 0.f;
    for (int k = 0; k < DD; ++k) { float d = xp[k] - yrow[k]; s = fmaf(d, d, s); }
    lmin = fminf(lmin, s);
  }
  #pragma unroll
  for (int off = 32; off; off >>= 1) lmin = fminf(lmin, __shfl_down(lmin, off, 64));
  if ((threadIdx.x & 63) == 0) wm[threadIdx.x >> 6] = lmin;
  __syncthreads();
  if (threadIdx.x == 0) {
    float mn = fminf(fminf(wm[0], wm[1]), fminf(wm[2], wm[3]));
    atomicMin(minp, __float_as_uint(fmaxf(mn, 0.0f)));
  }
}

__global__ __launch_bounds__(64) void k_finalize(const unsigned int* minp, float* out) {
  if (threadIdx.x == 0) out[0] = sqrtf(__uint_as_float(*minp));
}

extern "C" void kernel_launch(void* const* d_in, const int* in_sizes, int n_in,
                              void* d_out, int out_size, void* d_ws, size_t ws_size,
                              hipStream_t stream) {
  const float* pred = (const float*)d_in[0];
  const float* cand = (const float*)d_in[1];
  float* out = (float*)d_out;

  // ws layout: [0] min-bits | +16 floats: nx[2048] | ny[65536] | Abf bf16[2048*512] | Bbf bf16[65536*512]
  unsigned int* minp = (unsigned int*)d_ws;
  float* wsf = (float*)d_ws;
  float* nx = wsf + 16;
  float* ny = nx + P;
  unsigned short* Abf = (unsigned short*)(ny + R);
  unsigned short* Bbf = Abf + (size_t)P * DD;
  const size_t need = (size_t)(16 + P + R) * 4 + ((size_t)P * DD + (size_t)R * DD) * 2;

  if (ws_size >= need) {
    const int rows = P + R;                 // 67584 rows, 4 waves/block
    k_convert<<<rows / 4, 256, 0, stream>>>(pred, cand, Abf, Bbf, nx, ny, minp);
    k_gemm_min<<<(P / BM) * (R / BN), 256, 0, stream>>>(Abf, Bbf, nx, ny, minp);
  } else {
    k_initmin<<<1, 64, 0, stream>>>(minp);
    k_brute<<<R, 256, 0, stream>>>(pred, cand, minp);
  }
  k_finalize<<<1, 64, 0, stream>>>(minp, out);
}

// Round 4
// 347.973 us; speedup vs baseline: 1.0949x; 1.0949x over previous
//
#include <hip/hip_runtime.h>
#include <stdint.h>

#define P 2048
#define R 65536
#define DD 512
#define BM 256
#define BN 256
#define BK 64
#define NT (DD / BK)   // 8 K-tiles

typedef __attribute__((ext_vector_type(8))) short short8;
typedef __attribute__((ext_vector_type(4))) float f32x4;

__device__ inline unsigned short f2bf(float f) {
  unsigned int u = __float_as_uint(f);
  u += 0x7fffu + ((u >> 16) & 1u);   // round-to-nearest-even
  return (unsigned short)(u >> 16);
}

__device__ inline void gload_lds16(const void* g, void* l) {
  __builtin_amdgcn_global_load_lds(
      (const __attribute__((address_space(1))) unsigned int*)g,
      (__attribute__((address_space(3))) unsigned int*)l,
      16, 0, 0);
}

// ---- kernel 1: fp32 -> bf16 conversion + fp32 row norms; one wave per row,
//      grid-stride (2048 blocks, ~8 rows/wave) ----
__global__ __launch_bounds__(256) void k_convert(
    const float* __restrict__ pred, const float* __restrict__ cand,
    unsigned short* __restrict__ Abf, unsigned short* __restrict__ Bbf,
    float* __restrict__ nx, float* __restrict__ ny,
    unsigned int* __restrict__ minp)
{
  if (blockIdx.x == 0 && threadIdx.x == 0) *minp = 0x7f800000u; // +inf bits
  const int lane = threadIdx.x & 63;
  const int wv   = (blockIdx.x << 2) | (threadIdx.x >> 6);
  const int nw   = gridDim.x << 2;
  for (int gw = wv; gw < P + R; gw += nw) {
    const float* src; unsigned short* dst; float* np;
    if (gw < P) { src = pred + (size_t)gw * DD; dst = Abf + (size_t)gw * DD; np = nx + gw; }
    else { int r = gw - P; src = cand + (size_t)r * DD; dst = Bbf + (size_t)r * DD; np = ny + r; }
    const float4* s4 = ((const float4*)src) + lane * 2;
    float4 v0 = s4[0], v1 = s4[1];
    float ss = v0.x*v0.x + v0.y*v0.y + v0.z*v0.z + v0.w*v0.w
             + v1.x*v1.x + v1.y*v1.y + v1.z*v1.z + v1.w*v1.w;
    union { unsigned short h[8]; uint4 v; } pk;
    pk.h[0]=f2bf(v0.x); pk.h[1]=f2bf(v0.y); pk.h[2]=f2bf(v0.z); pk.h[3]=f2bf(v0.w);
    pk.h[4]=f2bf(v1.x); pk.h[5]=f2bf(v1.y); pk.h[6]=f2bf(v1.z); pk.h[7]=f2bf(v1.w);
    *(uint4*)(dst + (size_t)lane * 8) = pk.v;
    #pragma unroll
    for (int off = 32; off; off >>= 1) ss += __shfl_down(ss, off, 64);
    if (lane == 0) *np = ss;
  }
}

// ---- kernel 2: 256x256 bf16 MFMA GEMM (A·B^T), BK=64, 8 waves (2Mx4N),
//      double-buffered LDS, 2 barriers/tile, counted vmcnt(8) staging,
//      READ-AHEAD tile body with counted lgkmcnt (derived waits):
//        issue A0(8)+B0(4)+B1(4) -> lgkmcnt(4) -> MFMA Q0 (B1 lands under Q0)
//        -> lgkmcnt(0) -> MFMA Q1 -> issue A1(8, reuse A0 regs)
//        -> lgkmcnt(0) -> MFMA Q2+Q3
//      No intra-tile barriers: waves free-run, skew overlaps one wave's
//      reads with the other wave's MFMA on the same SIMD.
//      setprio around MFMA quads (T5), XCD swizzle (T1), chunk-XOR LDS
//      swizzle (T2, measured conflict-free), fused min epilogue.
//
// LDS: per operand/buffer row-major [256][64] bf16; 16B-chunks of each row
// stored permuted: stored_chunk = data_chunk ^ (row & 7), applied via the
// GLOBAL source address (linear gload_lds dest + inverse-swizzled source).
//
// Tile T: STAGE(T+1 -> buf s^1) [safe: everyone finished reading s^1 at
// T-1's end barrier]; vmcnt(8) [T's 8 loads landed, T+1's in flight];
// barrier [all waves' T-loads landed]; body (all 24 ds_reads drained by the
// last lgkmcnt(0) before the end barrier, so re-staging buf s at T+1 is safe];
// barrier.
__global__ __launch_bounds__(512, 2) void k_gemm_min(
    const unsigned short* __restrict__ Abf, const unsigned short* __restrict__ Bbf,
    const float* __restrict__ nx, const float* __restrict__ ny,
    unsigned int* __restrict__ minp)
{
  __shared__ __align__(16) unsigned short As[2][BM * BK];   // 2 x 32 KB
  __shared__ __align__(16) unsigned short Bs[2][BN * BK];   // 2 x 32 KB
  __shared__ float wmin[8];

  const int tid  = threadIdx.x;
  const int wave = tid >> 6;          // 0..7
  const int lane = tid & 63;

  // XCD-aware bijective remap: 2048 blocks, 8 XCDs, 256 contiguous per XCD.
  const int raw = blockIdx.x;
  const int wg  = (raw & 7) * 256 + (raw >> 3);
  const int by  = wg & 7;             // pred tile fast -> 8 adjacent wg share cand tile
  const int bx  = wg >> 3;            // cand tile
  const int rowA0 = by * BM, rowB0 = bx * BN;
  const int wr = wave >> 2;           // 0..1 : M half   (wave tile 128x64)
  const int wc = wave & 3;            // 0..3 : N quarter

  f32x4 zero = {0.f, 0.f, 0.f, 0.f};
  f32x4 acc[8][4];
  #pragma unroll
  for (int i = 0; i < 8; ++i)
    #pragma unroll
    for (int j = 0; j < 4; ++j) acc[i][j] = zero;

  // staging: per operand 32 wave-instrs (8 waves x t=0..3), each 8 rows x 64
  // cols (1 KB). lane L -> local row L>>3, stored chunk L&7, source data
  // chunk (L&7)^(L>>3).
  const int rloc = lane >> 3;
  const int cswz = (lane & 7) ^ rloc;
  const unsigned short* gA[4]; const unsigned short* gB[4];
  int lofs[4];
  #pragma unroll
  for (int t = 0; t < 4; ++t) {
    const int ii = wave * 4 + t;          // 0..31
    gA[t] = Abf + (size_t)(rowA0 + ii * 8 + rloc) * DD + cswz * 8;
    gB[t] = Bbf + (size_t)(rowB0 + ii * 8 + rloc) * DD + cswz * 8;
    lofs[t] = ii * 512;                   // shorts (1 KB per instr)
  }

#define STAGE(s, kt) do { const int _k0 = (kt) * BK;            \
    _Pragma("unroll")                                           \
    for (int _t = 0; _t < 4; ++_t) {                            \
      gload_lds16(gA[_t] + _k0, &As[s][lofs[_t]]);              \
      gload_lds16(gB[_t] + _k0, &Bs[s][lofs[_t]]);              \
    } } while (0)

  // fragment read geometry. A frag i: row wr*128 + i*16 + m; B frag j: row
  // wc*64 + j*16 + m; k-chunk (h*4+quad) stored at chunk ^ (m&7).
  const int m = lane & 15, quad = lane >> 4, mb = m & 7;
  const int aRow0 = (wr * 128 + m) * BK;
  const int bRow0 = (wc * 64  + m) * BK;
  const int swz0 = ((quad    ) ^ mb) * 8;
  const int swz1 = ((quad + 4) ^ mb) * 8;

  STAGE(0, 0);

  #pragma unroll 2
  for (int T = 0; T < NT; ++T) {
    const int s = T & 1;
    if (T + 1 < NT) {
      STAGE(s ^ 1, T + 1);
      asm volatile("s_waitcnt vmcnt(8)" ::: "memory");   // tile T landed
    } else {
      asm volatile("s_waitcnt vmcnt(0)" ::: "memory");
    }
    __builtin_amdgcn_s_barrier();
    __builtin_amdgcn_sched_barrier(0);

    const unsigned short* A0 = &As[s][0];
    const unsigned short* B0 = &Bs[s][0];
    short8 af[4][2], b0[2][2], b1[2][2];

    // issue A-half0 (8) + B-half0 (4) + B-half1 (4) — B1 rides under Q0
    #pragma unroll
    for (int i = 0; i < 4; ++i) {
      const unsigned short* ap = A0 + aRow0 + i * 16 * BK;
      af[i][0] = *(const short8*)(ap + swz0);
      af[i][1] = *(const short8*)(ap + swz1);
    }
    #pragma unroll
    for (int j = 0; j < 2; ++j) {
      const unsigned short* bp = B0 + bRow0 + j * 16 * BK;
      b0[j][0] = *(const short8*)(bp + swz0);
      b0[j][1] = *(const short8*)(bp + swz1);
    }
    #pragma unroll
    for (int j = 0; j < 2; ++j) {
      const unsigned short* bp = B0 + bRow0 + (2 + j) * 16 * BK;
      b1[j][0] = *(const short8*)(bp + swz0);
      b1[j][1] = *(const short8*)(bp + swz1);
    }
    asm volatile("s_waitcnt lgkmcnt(4)" ::: "memory");   // A0+B0 landed
    __builtin_amdgcn_sched_barrier(0);
    __builtin_amdgcn_s_setprio(1);
    #pragma unroll
    for (int i = 0; i < 4; ++i)
      #pragma unroll
      for (int j = 0; j < 2; ++j) {
        acc[i][j] = __builtin_amdgcn_mfma_f32_16x16x32_bf16(af[i][0], b0[j][0], acc[i][j], 0, 0, 0);
        acc[i][j] = __builtin_amdgcn_mfma_f32_16x16x32_bf16(af[i][1], b0[j][1], acc[i][j], 0, 0, 0);
      }
    __builtin_amdgcn_s_setprio(0);
    asm volatile("s_waitcnt lgkmcnt(0)" ::: "memory");   // B1 landed
    __builtin_amdgcn_sched_barrier(0);
    __builtin_amdgcn_s_setprio(1);
    #pragma unroll
    for (int i = 0; i < 4; ++i)
      #pragma unroll
      for (int j = 0; j < 2; ++j) {
        acc[i][2 + j] = __builtin_amdgcn_mfma_f32_16x16x32_bf16(af[i][0], b1[j][0], acc[i][2 + j], 0, 0, 0);
        acc[i][2 + j] = __builtin_amdgcn_mfma_f32_16x16x32_bf16(af[i][1], b1[j][1], acc[i][2 + j], 0, 0, 0);
      }
    __builtin_amdgcn_s_setprio(0);

    // A-half1 into the (now dead) A0 registers
    #pragma unroll
    for (int i = 0; i < 4; ++i) {
      const unsigned short* ap = A0 + aRow0 + (4 + i) * 16 * BK;
      af[i][0] = *(const short8*)(ap + swz0);
      af[i][1] = *(const short8*)(ap + swz1);
    }
    asm volatile("s_waitcnt lgkmcnt(0)" ::: "memory");   // A1 landed
    __builtin_amdgcn_sched_barrier(0);
    __builtin_amdgcn_s_setprio(1);
    #pragma unroll
    for (int i = 0; i < 4; ++i) {
      #pragma unroll
      for (int j = 0; j < 2; ++j) {
        acc[4 + i][j]     = __builtin_amdgcn_mfma_f32_16x16x32_bf16(af[i][0], b0[j][0], acc[4 + i][j], 0, 0, 0);
        acc[4 + i][j]     = __builtin_amdgcn_mfma_f32_16x16x32_bf16(af[i][1], b0[j][1], acc[4 + i][j], 0, 0, 0);
      }
      #pragma unroll
      for (int j = 0; j < 2; ++j) {
        acc[4 + i][2 + j] = __builtin_amdgcn_mfma_f32_16x16x32_bf16(af[i][0], b1[j][0], acc[4 + i][2 + j], 0, 0, 0);
        acc[4 + i][2 + j] = __builtin_amdgcn_mfma_f32_16x16x32_bf16(af[i][1], b1[j][1], acc[4 + i][2 + j], 0, 0, 0);
      }
    }
    __builtin_amdgcn_s_setprio(0);
    __builtin_amdgcn_s_barrier();       // reads done before anyone re-stages buf s
  }
#undef STAGE

  // epilogue: d^2 = ||x||^2 + ||y||^2 - 2*dot ; C/D layout col=lane&15, row=quad*4+reg
  float lmin = 3.4e38f;
  #pragma unroll
  for (int i = 0; i < 8; ++i) {
    const int mbase = rowA0 + wr * 128 + i * 16 + quad * 4;
    float4 nxv = *(const float4*)(nx + mbase);
    #pragma unroll
    for (int j = 0; j < 4; ++j) {
      const int n = rowB0 + wc * 64 + j * 16 + m;
      const float nyv = ny[n];
      f32x4 a = acc[i][j];
      lmin = fminf(lmin, nxv.x + nyv - 2.0f * a[0]);
      lmin = fminf(lmin, nxv.y + nyv - 2.0f * a[1]);
      lmin = fminf(lmin, nxv.z + nyv - 2.0f * a[2]);
      lmin = fminf(lmin, nxv.w + nyv - 2.0f * a[3]);
    }
  }
  #pragma unroll
  for (int off = 32; off; off >>= 1) lmin = fminf(lmin, __shfl_down(lmin, off, 64));
  if (lane == 0) wmin[wave] = lmin;
  __syncthreads();
  if (tid == 0) {
    float mn = wmin[0];
    #pragma unroll
    for (int w = 1; w < 8; ++w) mn = fminf(mn, wmin[w]);
    atomicMin(minp, __float_as_uint(fmaxf(mn, 0.0f)));
  }
}

// ---- fallback (only if ws too small): exact fp32 brute force ----
__global__ __launch_bounds__(64) void k_initmin(unsigned int* minp) {
  if (threadIdx.x == 0) *minp = 0x7f800000u;
}

__global__ __launch_bounds__(256) void k_brute(
    const float* __restrict__ pred, const float* __restrict__ cand,
    unsigned int* __restrict__ minp)
{
  __shared__ float yrow[DD];
  __shared__ float wm[4];
  const int c = blockIdx.x;
  for (int i = threadIdx.x; i < DD; i += 256) yrow[i] = cand[(size_t)c * DD + i];
  __syncthreads();
  float lmin = 3.4e38f;
  for (int p = threadIdx.x; p < P; p += 256) {
    const float* xp = pred + (size_t)p * DD;
    float s = 0.f;
    for (int k = 0; k < DD; ++k) { float d = xp[k] - yrow[k]; s = fmaf(d, d, s); }
    lmin = fminf(lmin, s);
  }
  #pragma unroll
  for (int off = 32; off; off >>= 1) lmin = fminf(lmin, __shfl_down(lmin, off, 64));
  if ((threadIdx.x & 63) == 0) wm[threadIdx.x >> 6] = lmin;
  __syncthreads();
  if (threadIdx.x == 0) {
    float mn = fminf(fminf(wm[0], wm[1]), fminf(wm[2], wm[3]));
    atomicMin(minp, __float_as_uint(fmaxf(mn, 0.0f)));
  }
}

__global__ __launch_bounds__(64) void k_finalize(const unsigned int* minp, float* out) {
  if (threadIdx.x == 0) out[0] = sqrtf(__uint_as_float(*minp));
}

extern "C" void kernel_launch(void* const* d_in, const int* in_sizes, int n_in,
                              void* d_out, int out_size, void* d_ws, size_t ws_size,
                              hipStream_t stream) {
  const float* pred = (const float*)d_in[0];
  const float* cand = (const float*)d_in[1];
  float* out = (float*)d_out;

  // ws layout: [0] min-bits | +16 floats: nx[2048] | ny[65536] | Abf bf16[2048*512] | Bbf bf16[65536*512]
  unsigned int* minp = (unsigned int*)d_ws;
  float* wsf = (float*)d_ws;
  float* nx = wsf + 16;
  float* ny = nx + P;
  unsigned short* Abf = (unsigned short*)(ny + R);
  unsigned short* Bbf = Abf + (size_t)P * DD;
  const size_t need = (size_t)(16 + P + R) * 4 + ((size_t)P * DD + (size_t)R * DD) * 2;

  if (ws_size >= need) {
    k_convert<<<2048, 256, 0, stream>>>(pred, cand, Abf, Bbf, nx, ny, minp);
    k_gemm_min<<<(P / BM) * (R / BN), 512, 0, stream>>>(Abf, Bbf, nx, ny, minp);
  } else {
    k_initmin<<<1, 64, 0, stream>>>(minp);
    k_brute<<<R, 256, 0, stream>>>(pred, cand, minp);
  }
  k_finalize<<<1, 64, 0, stream>>>(minp, out);
}

// Round 5
// 347.833 us; speedup vs baseline: 1.0953x; 1.0004x over previous
//
#include <hip/hip_runtime.h>
#include <stdint.h>

#define P 2048
#define R 65536
#define DD 512
#define BM 256
#define BN 256
#define BK 64
#define NT (DD / BK)   // 8 K-tiles

typedef __attribute__((ext_vector_type(8))) short short8;
typedef __attribute__((ext_vector_type(4))) float f32x4;
typedef __attribute__((ext_vector_type(16))) float f32x16;

__device__ inline unsigned short f2bf(float f) {
  unsigned int u = __float_as_uint(f);
  u += 0x7fffu + ((u >> 16) & 1u);   // round-to-nearest-even
  return (unsigned short)(u >> 16);
}

__device__ inline void gload_lds16(const void* g, void* l) {
  __builtin_amdgcn_global_load_lds(
      (const __attribute__((address_space(1))) unsigned int*)g,
      (__attribute__((address_space(3))) unsigned int*)l,
      16, 0, 0);
}

// ---- kernel 1: fp32 -> bf16 conversion + fp32 row norms; one wave per row,
//      grid-stride (2048 blocks, ~8 rows/wave) ----
__global__ __launch_bounds__(256) void k_convert(
    const float* __restrict__ pred, const float* __restrict__ cand,
    unsigned short* __restrict__ Abf, unsigned short* __restrict__ Bbf,
    float* __restrict__ nx, float* __restrict__ ny,
    unsigned int* __restrict__ minp)
{
  if (blockIdx.x == 0 && threadIdx.x == 0) *minp = 0x7f800000u; // +inf bits
  const int lane = threadIdx.x & 63;
  const int wv   = (blockIdx.x << 2) | (threadIdx.x >> 6);
  const int nw   = gridDim.x << 2;
  for (int gw = wv; gw < P + R; gw += nw) {
    const float* src; unsigned short* dst; float* np;
    if (gw < P) { src = pred + (size_t)gw * DD; dst = Abf + (size_t)gw * DD; np = nx + gw; }
    else { int r = gw - P; src = cand + (size_t)r * DD; dst = Bbf + (size_t)r * DD; np = ny + r; }
    const float4* s4 = ((const float4*)src) + lane * 2;
    float4 v0 = s4[0], v1 = s4[1];
    float ss = v0.x*v0.x + v0.y*v0.y + v0.z*v0.z + v0.w*v0.w
             + v1.x*v1.x + v1.y*v1.y + v1.z*v1.z + v1.w*v1.w;
    union { unsigned short h[8]; uint4 v; } pk;
    pk.h[0]=f2bf(v0.x); pk.h[1]=f2bf(v0.y); pk.h[2]=f2bf(v0.z); pk.h[3]=f2bf(v0.w);
    pk.h[4]=f2bf(v1.x); pk.h[5]=f2bf(v1.y); pk.h[6]=f2bf(v1.z); pk.h[7]=f2bf(v1.w);
    *(uint4*)(dst + (size_t)lane * 8) = pk.v;
    #pragma unroll
    for (int off = 32; off; off >>= 1) ss += __shfl_down(ss, off, 64);
    if (lane == 0) *np = ss;
  }
}

// ---- kernel 2: 256x256 bf16 MFMA GEMM (A·B^T), BK=64, 8 waves (2Mx4N),
//      *** 32x32x16 MFMA *** (2495 TF ceiling vs 2075 for 16x16x32; 4x fewer
//      MFMA instructions), double-buffered LDS, 2 barriers/tile, counted
//      vmcnt(8) staging, 1-k-step register lookahead with counted lgkmcnt(6),
//      setprio, XCD swizzle, chunk-XOR LDS swizzle, fused min epilogue.
//
// LDS: per operand/buffer row-major [256][64] bf16; 16B-chunks of each row
// stored permuted: stored_chunk = data_chunk ^ (row & 7), applied via the
// GLOBAL source address (linear gload_lds dest + inverse-swizzled source).
//
// 32x32x16 fragments: A/B row = lane&31 (within 32-row tile), k-elems
// (lane>>5)*8 .. +8 of the 16-wide k-step -> data chunk = ks*2 + (lane>>5),
// stored chunk = (ks*2+h) ^ (lane&7)  [tile bases are 32-aligned so
// row&7 == lane&7]. Bank check: each aligned 8-lane group has lane&7=0..7 ->
// 8 distinct stored chunks -> conflict-free (same invariant as the measured-
// zero-conflict 16x16 pattern; SQ_LDS_BANK_CONFLICT verifies).
// C/D layout (m74/m101): col = lane&31, row = (reg&3) + 8*(reg>>2) + 4*(lane>>5).
//
// Per K-tile per wave: 4 k-steps x { 4 A-frag + 2 B-frag b128 reads, 8 MFMA }.
// k-step pipeline: read ks0+ks1 -> lgkm(6) -> MFMA ks0 -> read ks2 ->
// lgkm(6) -> MFMA ks1 -> read ks3 -> lgkm(6) -> MFMA ks2 -> lgkm(0) -> MFMA ks3.
__global__ __launch_bounds__(512, 2) void k_gemm_min(
    const unsigned short* __restrict__ Abf, const unsigned short* __restrict__ Bbf,
    const float* __restrict__ nx, const float* __restrict__ ny,
    unsigned int* __restrict__ minp)
{
  __shared__ __align__(16) unsigned short As[2][BM * BK];   // 2 x 32 KB
  __shared__ __align__(16) unsigned short Bs[2][BN * BK];   // 2 x 32 KB
  __shared__ float wmin[8];

  const int tid  = threadIdx.x;
  const int wave = tid >> 6;          // 0..7
  const int lane = tid & 63;

  // XCD-aware bijective remap: 2048 blocks, 8 XCDs, 256 contiguous per XCD.
  const int raw = blockIdx.x;
  const int wg  = (raw & 7) * 256 + (raw >> 3);
  const int by  = wg & 7;             // pred tile fast -> 8 adjacent wg share cand tile
  const int bx  = wg >> 3;            // cand tile
  const int rowA0 = by * BM, rowB0 = bx * BN;
  const int wr = wave >> 2;           // 0..1 : M half   (wave tile 128x64)
  const int wc = wave & 3;            // 0..3 : N quarter

  f32x16 acc[4][2];
  #pragma unroll
  for (int i = 0; i < 4; ++i)
    #pragma unroll
    for (int j = 0; j < 2; ++j)
      #pragma unroll
      for (int r = 0; r < 16; ++r) acc[i][j][r] = 0.f;

  // staging: per operand 32 wave-instrs (8 waves x t=0..3), each 8 rows x 64
  // cols (1 KB). lane L -> local row L>>3, stored chunk L&7, source data
  // chunk (L&7)^(L>>3).
  const int rloc = lane >> 3;
  const int cswz = (lane & 7) ^ rloc;
  const unsigned short* gA[4]; const unsigned short* gB[4];
  int lofs[4];
  #pragma unroll
  for (int t = 0; t < 4; ++t) {
    const int ii = wave * 4 + t;          // 0..31
    gA[t] = Abf + (size_t)(rowA0 + ii * 8 + rloc) * DD + cswz * 8;
    gB[t] = Bbf + (size_t)(rowB0 + ii * 8 + rloc) * DD + cswz * 8;
    lofs[t] = ii * 512;                   // shorts (1 KB per instr)
  }

#define STAGE(s, kt) do { const int _k0 = (kt) * BK;            \
    _Pragma("unroll")                                           \
    for (int _t = 0; _t < 4; ++_t) {                            \
      gload_lds16(gA[_t] + _k0, &As[s][lofs[_t]]);              \
      gload_lds16(gB[_t] + _k0, &Bs[s][lofs[_t]]);              \
    } } while (0)

  // fragment read geometry (32x32x16)
  const int col31 = lane & 31, h = lane >> 5;
  const int aBase0 = (wr * 128 + col31) * BK;   // shorts
  const int bBase0 = (wc * 64  + col31) * BK;
  int swks[4];
  #pragma unroll
  for (int ks = 0; ks < 4; ++ks) swks[ks] = ((ks * 2 + h) ^ (lane & 7)) * 8;

#define READ(aR, bR, s, ks) do {                                              \
    _Pragma("unroll")                                                         \
    for (int _i = 0; _i < 4; ++_i)                                            \
      aR[_i] = *(const short8*)(&As[s][aBase0 + _i * 32 * BK + swks[ks]]);    \
    _Pragma("unroll")                                                         \
    for (int _j = 0; _j < 2; ++_j)                                            \
      bR[_j] = *(const short8*)(&Bs[s][bBase0 + _j * 32 * BK + swks[ks]]);    \
  } while (0)

#define MFMA8(aR, bR) do {                                                    \
    __builtin_amdgcn_s_setprio(1);                                            \
    _Pragma("unroll")                                                         \
    for (int _i = 0; _i < 4; ++_i)                                            \
      _Pragma("unroll")                                                       \
      for (int _j = 0; _j < 2; ++_j)                                          \
        acc[_i][_j] = __builtin_amdgcn_mfma_f32_32x32x16_bf16(                \
            aR[_i], bR[_j], acc[_i][_j], 0, 0, 0);                            \
    __builtin_amdgcn_s_setprio(0);                                            \
  } while (0)

  STAGE(0, 0);

  #pragma unroll 2
  for (int T = 0; T < NT; ++T) {
    const int s = T & 1;
    if (T + 1 < NT) {
      STAGE(s ^ 1, T + 1);
      asm volatile("s_waitcnt vmcnt(8)" ::: "memory");   // tile T landed
    } else {
      asm volatile("s_waitcnt vmcnt(0)" ::: "memory");
    }
    __builtin_amdgcn_s_barrier();
    __builtin_amdgcn_sched_barrier(0);

    short8 aX[4], bX[2], aY[4], bY[2];
    READ(aX, bX, s, 0);
    READ(aY, bY, s, 1);
    asm volatile("s_waitcnt lgkmcnt(6)" ::: "memory");   // ks0 landed
    __builtin_amdgcn_sched_barrier(0);
    MFMA8(aX, bX);                                       // ks0
    READ(aX, bX, s, 2);
    asm volatile("s_waitcnt lgkmcnt(6)" ::: "memory");   // ks1 landed
    __builtin_amdgcn_sched_barrier(0);
    MFMA8(aY, bY);                                       // ks1
    READ(aY, bY, s, 3);
    asm volatile("s_waitcnt lgkmcnt(6)" ::: "memory");   // ks2 landed
    __builtin_amdgcn_sched_barrier(0);
    MFMA8(aX, bX);                                       // ks2
    asm volatile("s_waitcnt lgkmcnt(0)" ::: "memory");   // ks3 landed
    __builtin_amdgcn_sched_barrier(0);
    MFMA8(aY, bY);                                       // ks3
    __builtin_amdgcn_s_barrier();       // reads done before anyone re-stages buf s
  }
#undef STAGE
#undef READ
#undef MFMA8

  // epilogue: d^2 = ||x||^2 + ||y||^2 - 2*dot
  // C/D: col = lane&31, row = (reg&3) + 8*(reg>>2) + 4*h
  float lmin = 3.4e38f;
  #pragma unroll
  for (int i = 0; i < 4; ++i) {
    #pragma unroll
    for (int rq = 0; rq < 4; ++rq) {
      const int mbase = rowA0 + wr * 128 + i * 32 + rq * 8 + h * 4;
      float4 nxv = *(const float4*)(nx + mbase);
      #pragma unroll
      for (int j = 0; j < 2; ++j) {
        const int n = rowB0 + wc * 64 + j * 32 + col31;
        const float nyv = ny[n];
        lmin = fminf(lmin, nxv.x + nyv - 2.0f * acc[i][j][rq * 4 + 0]);
        lmin = fminf(lmin, nxv.y + nyv - 2.0f * acc[i][j][rq * 4 + 1]);
        lmin = fminf(lmin, nxv.z + nyv - 2.0f * acc[i][j][rq * 4 + 2]);
        lmin = fminf(lmin, nxv.w + nyv - 2.0f * acc[i][j][rq * 4 + 3]);
      }
    }
  }
  #pragma unroll
  for (int off = 32; off; off >>= 1) lmin = fminf(lmin, __shfl_down(lmin, off, 64));
  if (lane == 0) wmin[wave] = lmin;
  __syncthreads();
  if (tid == 0) {
    float mn = wmin[0];
    #pragma unroll
    for (int w = 1; w < 8; ++w) mn = fminf(mn, wmin[w]);
    atomicMin(minp, __float_as_uint(fmaxf(mn, 0.0f)));
  }
}

// ---- fallback (only if ws too small): exact fp32 brute force ----
__global__ __launch_bounds__(64) void k_initmin(unsigned int* minp) {
  if (threadIdx.x == 0) *minp = 0x7f800000u;
}

__global__ __launch_bounds__(256) void k_brute(
    const float* __restrict__ pred, const float* __restrict__ cand,
    unsigned int* __restrict__ minp)
{
  __shared__ float yrow[DD];
  __shared__ float wm[4];
  const int c = blockIdx.x;
  for (int i = threadIdx.x; i < DD; i += 256) yrow[i] = cand[(size_t)c * DD + i];
  __syncthreads();
  float lmin = 3.4e38f;
  for (int p = threadIdx.x; p < P; p += 256) {
    const float* xp = pred + (size_t)p * DD;
    float s = 0.f;
    for (int k = 0; k < DD; ++k) { float d = xp[k] - yrow[k]; s = fmaf(d, d, s); }
    lmin = fminf(lmin, s);
  }
  #pragma unroll
  for (int off = 32; off; off >>= 1) lmin = fminf(lmin, __shfl_down(lmin, off, 64));
  if ((threadIdx.x & 63) == 0) wm[threadIdx.x >> 6] = lmin;
  __syncthreads();
  if (threadIdx.x == 0) {
    float mn = fminf(fminf(wm[0], wm[1]), fminf(wm[2], wm[3]));
    atomicMin(minp, __float_as_uint(fmaxf(mn, 0.0f)));
  }
}

__global__ __launch_bounds__(64) void k_finalize(const unsigned int* minp, float* out) {
  if (threadIdx.x == 0) out[0] = sqrtf(__uint_as_float(*minp));
}

extern "C" void kernel_launch(void* const* d_in, const int* in_sizes, int n_in,
                              void* d_out, int out_size, void* d_ws, size_t ws_size,
                              hipStream_t stream) {
  const float* pred = (const float*)d_in[0];
  const float* cand = (const float*)d_in[1];
  float* out = (float*)d_out;

  // ws layout: [0] min-bits | +16 floats: nx[2048] | ny[65536] | Abf bf16[2048*512] | Bbf bf16[65536*512]
  unsigned int* minp = (unsigned int*)d_ws;
  float* wsf = (float*)d_ws;
  float* nx = wsf + 16;
  float* ny = nx + P;
  unsigned short* Abf = (unsigned short*)(ny + R);
  unsigned short* Bbf = Abf + (size_t)P * DD;
  const size_t need = (size_t)(16 + P + R) * 4 + ((size_t)P * DD + (size_t)R * DD) * 2;

  if (ws_size >= need) {
    k_convert<<<2048, 256, 0, stream>>>(pred, cand, Abf, Bbf, nx, ny, minp);
    k_gemm_min<<<(P / BM) * (R / BN), 512, 0, stream>>>(Abf, Bbf, nx, ny, minp);
  } else {
    k_initmin<<<1, 64, 0, stream>>>(minp);
    k_brute<<<R, 256, 0, stream>>>(pred, cand, minp);
  }
  k_finalize<<<1, 64, 0, stream>>>(minp, out);
}